// Round 8
// baseline (271.858 us; speedup 1.0000x reference)
//
#include <hip/hip_runtime.h>
#include <hip/hip_bf16.h>

// Problem constants (reference: DIM=768, NUM_HEADS=12, HEAD_DIM=64, GRID=32, B=8)
#define B_   8
#define N_   1024
#define C_   768
#define NH_  12
#define HD_  64
#define BH_  96
#define EPS_ 1e-6f
#define EPSN_ (1e-6f / 1024.0f)
#define SQ_  0.1803368801111244f   // 0.125 * log2(e) — Q pre-scale

typedef __bf16 bf16;
typedef __attribute__((ext_vector_type(8))) __bf16  bf16x8;
typedef __attribute__((ext_vector_type(4))) __bf16  bf16x4;
typedef __attribute__((ext_vector_type(4))) float   floatx4;

#define MFMA16(a, b, c) __builtin_amdgcn_mfma_f32_16x16x32_bf16((a), (b), (c), 0, 0, 0)

__device__ __forceinline__ void gld16(const void* g, void* l) {
  typedef unsigned int u32;
  __builtin_amdgcn_global_load_lds(
      (const __attribute__((address_space(1))) u32*)g,
      (__attribute__((address_space(3))) u32*)l, 16, 0, 0);
}
__device__ __forceinline__ float bfu2f(unsigned int u) {   // low 16 bits = bf16
  union { unsigned int i; float f; } v; v.i = u << 16; return v.f;
}
__device__ __forceinline__ float bfhi2f(unsigned int u) {  // high 16 bits = bf16
  union { unsigned int i; float f; } v; v.i = u & 0xffff0000u; return v.f;
}
__device__ __forceinline__ unsigned short f2bfu(float f) {
  union { float f; unsigned int i; } v; v.f = f;
  return (unsigned short)((v.i + 0x7FFFu + ((v.i >> 16) & 1u)) >> 16);
}

// ---------------------------------------------------------------------------
// Fused prep: x/qkv_w/proj_w fp32->bf16, rel tables fp32->bf16 scaled by 8.
// ---------------------------------------------------------------------------
__global__ __launch_bounds__(256) void prep_kernel(
    const float* __restrict__ x, const float* __restrict__ qkv_w,
    const float* __restrict__ proj_w, const float* __restrict__ relh,
    const float* __restrict__ relw,
    bf16* __restrict__ Xb, bf16* __restrict__ Wq, bf16* __restrict__ Wp,
    bf16* __restrict__ Rhb, bf16* __restrict__ Rwb) {
  int bid = blockIdx.x;
  if (bid < 8448) {                 // bulk converts
    const float* in; bf16* out; int i;
    if (bid < 6144)      { in = x;      out = Xb; i = bid * 256 + threadIdx.x; }
    else if (bid < 7872) { in = qkv_w;  out = Wq; i = (bid - 6144) * 256 + threadIdx.x; }
    else                 { in = proj_w; out = Wp; i = (bid - 7872) * 256 + threadIdx.x; }
    float4 v = ((const float4*)in)[i];
    bf16x4 o = {(bf16)v.x, (bf16)v.y, (bf16)v.z, (bf16)v.w};
    ((bf16x4*)out)[i] = o;
  } else {                          // rel tables: 63x64 -> 64x64, x8 scale
    const float* in = (bid < 8464) ? relh : relw;
    bf16* out = (bid < 8464) ? Rhb : Rwb;
    int i = ((bid < 8464) ? (bid - 8448) : (bid - 8464)) * 256 + threadIdx.x;
    int r = i >> 6;
    out[i] = (r < 63) ? (bf16)(in[i] * 8.0f) : (bf16)0.0f;
  }
}

// ---------------------------------------------------------------------------
// QKV GEMM (m97 recipe). Q/K blocks flipped (packed d stores); V blocks
// normal (packed n stores into [bh][d][n]) + fused column-sum -> atomicAdd
// into Vsum[bh][d] (Vsum zeroed by hipMemsetAsync before launch).
// ---------------------------------------------------------------------------
__global__ __launch_bounds__(256) void gemm_qkv(
    const bf16* __restrict__ X, const bf16* __restrict__ W,
    const float* __restrict__ bias,
    bf16* __restrict__ Qb, bf16* __restrict__ Kb, bf16* __restrict__ Vb,
    float* __restrict__ Vsum) {
  __shared__ __align__(16) bf16 As[128 * 64];
  __shared__ __align__(16) bf16 Bs[128 * 64];
  const int tid = threadIdx.x;
  const int lane = tid & 63, quad = lane >> 4, c16 = lane & 15;
  const int wid = tid >> 6;
  const int wm = (wid >> 1) * 64, wn = (wid & 1) * 64;
  const int m0 = blockIdx.x * 128, n0 = blockIdx.y * 128;
  const bool flip = (blockIdx.y < 12);    // Q and K column blocks
  floatx4 acc[4][4];
#pragma unroll
  for (int i = 0; i < 4; ++i)
#pragma unroll
    for (int j = 0; j < 4; ++j) acc[i][j] = {0.f, 0.f, 0.f, 0.f};

  for (int k0 = 0; k0 < 768; k0 += 64) {
    __syncthreads();
#pragma unroll
    for (int t = 0; t < 4; ++t) {
      int task = t * 256 + tid;
      int r = task >> 3, lg = (task & 7) ^ (r & 7);
      int wbase = (t * 256 + (tid & 192)) * 8;
      gld16(X + (size_t)(m0 + r) * 768 + k0 + lg * 8, &As[wbase]);
      gld16(W + (size_t)(n0 + r) * 768 + k0 + lg * 8, &Bs[wbase]);
    }
    __syncthreads();
#pragma unroll
    for (int kw = 0; kw < 2; ++kw) {
      bf16x8 af[4], bfr[4];
#pragma unroll
      for (int i = 0; i < 4; ++i) {
        int r = wm + i * 16 + c16, pg = (kw * 4 + quad) ^ (c16 & 7);
        af[i] = *(bf16x8*)&As[r * 64 + pg * 8];
      }
#pragma unroll
      for (int j = 0; j < 4; ++j) {
        int r = wn + j * 16 + c16, pg = (kw * 4 + quad) ^ (c16 & 7);
        bfr[j] = *(bf16x8*)&Bs[r * 64 + pg * 8];
      }
      if (flip) {
#pragma unroll
        for (int a = 0; a < 4; ++a)
#pragma unroll
          for (int b = 0; b < 4; ++b) acc[a][b] = MFMA16(bfr[a], af[b], acc[a][b]);
      } else {
#pragma unroll
        for (int i = 0; i < 4; ++i)
#pragma unroll
          for (int j = 0; j < 4; ++j) acc[i][j] = MFMA16(af[i], bfr[j], acc[i][j]);
      }
    }
  }
  if (flip) {
    const bool isQ = (blockIdx.y < 6);
    bf16* base = isQ ? Qb : Kb;
    const int off = isQ ? 0 : 768;
#pragma unroll
    for (int a = 0; a < 4; ++a) {
      int jb = n0 + wn + a * 16 + quad * 4;
      float4 b4 = *(const float4*)&bias[jb];
      int head = (jb - off) >> 6;
      int d = jb & 63;
#pragma unroll
      for (int b = 0; b < 4; ++b) {
        int tok = m0 + wm + b * 16 + c16;
        int bb = tok >> 10, n = tok & 1023;
        float v0 = acc[a][b][0] + b4.x, v1 = acc[a][b][1] + b4.y;
        float v2 = acc[a][b][2] + b4.z, v3 = acc[a][b][3] + b4.w;
        if (isQ) { v0 *= SQ_; v1 *= SQ_; v2 *= SQ_; v3 *= SQ_; }
        bf16x4 o = {(bf16)v0, (bf16)v1, (bf16)v2, (bf16)v3};
        *(bf16x4*)&base[(((size_t)bb * NH_ + head) * N_ + n) * HD_ + d] = o;
      }
    }
  } else {
    const int bb = (m0 + wm) >> 10;     // wave's 64 tokens all in one batch
#pragma unroll
    for (int jt = 0; jt < 4; ++jt) {
      int j = n0 + wn + jt * 16 + c16;
      float bj = bias[j];
      int rem = j - 1536, head = rem >> 6, d = rem & 63;
      float colsum = 16.0f * bj;
#pragma unroll
      for (int it = 0; it < 4; ++it) {
        int mbase = m0 + wm + it * 16 + quad * 4;
        int n = mbase & 1023;
        bf16x4 o = {(bf16)(acc[it][jt][0] + bj), (bf16)(acc[it][jt][1] + bj),
                    (bf16)(acc[it][jt][2] + bj), (bf16)(acc[it][jt][3] + bj)};
        *(bf16x4*)&Vb[(((size_t)bb * NH_ + head) * HD_ + d) * N_ + n] = o;
        colsum += acc[it][jt][0] + acc[it][jt][1] + acc[it][jt][2] + acc[it][jt][3];
      }
      colsum += __shfl_xor(colsum, 16, 64);
      colsum += __shfl_xor(colsum, 32, 64);
      if (quad == 0) atomicAdd(&Vsum[(bb * NH_ + head) * HD_ + d], colsum);
    }
  }
}

// ---------------------------------------------------------------------------
// Flash attention, MFMA, 128-q blocks (512 thr / 8 waves), S^T orientation:
// S^T = K.Q^T -> C-layout holds 4 consecutive k per lane -> packed b64 P-strip
// writes, per-lane row-sum, float4 policy reads. rel-pos folded into C-init.
// LDS 54.3KB -> 3 blocks/CU (24 waves).
// ---------------------------------------------------------------------------
__global__ __launch_bounds__(512, 4) void attn_mfma(
    const bf16* __restrict__ Qb, const bf16* __restrict__ Kb,
    const bf16* __restrict__ Vb, const float* __restrict__ policy,
    const bf16* __restrict__ Rh, const bf16* __restrict__ Rw,
    const float* __restrict__ Vsum, bf16* __restrict__ AO) {
  const int bh = blockIdx.x, qt = blockIdx.y;      // qt: 128-q tile, 0..7
  const int b = bh / NH_, head = bh % NH_;
  __shared__ __align__(16) bf16 Qs[8192];          // 128x64; aliased by 8 P-strips
  __shared__ __align__(16) bf16 Ks[4096];          // Rh, Rw, then K tiles
  __shared__ __align__(16) bf16 Vt[4096];          // V tile [d][k]
  __shared__ unsigned short RHb[128][34];
  __shared__ unsigned short RWb[128][34];
  __shared__ float polf[1024];
  const int tid = threadIdx.x;
  const int wid = tid >> 6, lane = tid & 63, quad = lane >> 4, c16 = lane & 15;
  const int sw = c16 & 7;
  bf16* Ptw = Qs + wid * 1024;                     // wave-private [16][64] strip
  const floatx4 zero4 = {0.f, 0.f, 0.f, 0.f};

  const bf16* Qg = Qb + ((size_t)bh * N_ + qt * 128) * HD_;
  const bf16* Kg = Kb + (size_t)bh * (N_ * HD_);
  const bf16* Vg = Vb + (size_t)bh * (N_ * HD_);

  // stage Q (128x64), Rh (into Ks), policy row
#pragma unroll
  for (int t = 0; t < 2; ++t) {
    int task = t * 512 + tid;
    int r = task >> 3, lg = (task & 7) ^ (r & 7);
    gld16(Qg + r * 64 + lg * 8, &Qs[(t * 512 + (tid & 448)) * 8]);
  }
  {
    int r = tid >> 3, lg = (tid & 7) ^ (r & 7);
    gld16(Rh + r * 64 + lg * 8, &Ks[(tid & 448) * 8]);
  }
  if (tid < 256) gld16(policy + (size_t)b * N_ + tid * 4, &polf[(tid & 192) * 4]);
  __syncthreads();

  // Q fragments: serve as A-operand (rel phase) AND B-operand (S^T) — same reads
  bf16x8 aq0 = *(bf16x8*)&Qs[(wid * 16 + c16) * 64 + (quad ^ sw) * 8];
  bf16x8 aq1 = *(bf16x8*)&Qs[(wid * 16 + c16) * 64 + ((4 + quad) ^ sw) * 8];

  // QRh -> RHb[rloc][krow]  (rows wave-private)
  {
    floatx4 racc[4];
#pragma unroll
    for (int nt = 0; nt < 4; ++nt) {
      int r = nt * 16 + c16;
      bf16x8 b0 = *(bf16x8*)&Ks[r * 64 + (quad ^ sw) * 8];
      bf16x8 b1 = *(bf16x8*)&Ks[r * 64 + ((4 + quad) ^ sw) * 8];
      racc[nt] = MFMA16(aq1, b1, MFMA16(aq0, b0, zero4));
    }
#pragma unroll
    for (int nt = 0; nt < 4; ++nt)
#pragma unroll
      for (int reg = 0; reg < 4; ++reg) {
        int rloc = wid * 16 + quad * 4 + reg;
        int hh = qt * 4 + (rloc >> 5);
        int krow = hh + 31 - (nt * 16 + c16);
        if ((unsigned)krow < 32u) RHb[rloc][krow] = f2bfu(racc[nt][reg]);
      }
  }
  __syncthreads();
  {
    int r = tid >> 3, lg = (tid & 7) ^ (r & 7);
    gld16(Rw + r * 64 + lg * 8, &Ks[(tid & 448) * 8]);
  }
  __syncthreads();
  // QRw -> RWb[rloc][kcol]
  {
    floatx4 racc[4];
#pragma unroll
    for (int nt = 0; nt < 4; ++nt) {
      int r = nt * 16 + c16;
      bf16x8 b0 = *(bf16x8*)&Ks[r * 64 + (quad ^ sw) * 8];
      bf16x8 b1 = *(bf16x8*)&Ks[r * 64 + ((4 + quad) ^ sw) * 8];
      racc[nt] = MFMA16(aq1, b1, MFMA16(aq0, b0, zero4));
    }
#pragma unroll
    for (int nt = 0; nt < 4; ++nt)
#pragma unroll
      for (int reg = 0; reg < 4; ++reg) {
        int rloc = wid * 16 + quad * 4 + reg;
        int kcol = (rloc & 31) + 31 - (nt * 16 + c16);
        if ((unsigned)kcol < 32u) RWb[rloc][kcol] = f2bfu(racc[nt][reg]);
      }
  }

  // per-lane q (S^T column): qloc = wid*16+c16; hoist rw values (8, kt-invariant)
  const int qloc = wid * 16 + c16;
  float rwv[2][4];
#pragma unroll
  for (int p = 0; p < 2; ++p)
#pragma unroll
    for (int reg = 0; reg < 4; ++reg)
      rwv[p][reg] = bfu2f(RWb[qloc][p * 16 + quad * 4 + reg]);
  // P-strip write offsets (kt-invariant): row c16, k = nt*16+quad*4 (b64)
  int ptoff[4];
#pragma unroll
  for (int nt = 0; nt < 4; ++nt)
    ptoff[nt] = c16 * 64 + (((nt * 2 + (quad >> 1)) ^ sw) << 3) + ((quad & 1) << 2);
  const int ktq = qt * 2 + (wid >> 2);          // diagonal k-tile (wave-uniform)
  const int kdiag = (wid & 3) * 16 + c16;       // k-local hit in that tile

  float l_lane = 0.f;
  floatx4 o_acc[4];
#pragma unroll
  for (int i = 0; i < 4; ++i) o_acc[i] = zero4;

  for (int kt = 0; kt < 16; ++kt) {
    __syncthreads();
    {
      int r = tid >> 3, lg = (tid & 7) ^ (r & 7);
      int wbase = (tid & 448) * 8;
      gld16(Kg + (size_t)(kt * 64 + r) * 64 + lg * 8, &Ks[wbase]);
      gld16(Vg + (size_t)r * N_ + kt * 64 + lg * 8, &Vt[wbase]);
    }
    // rh pair for this tile (same-wave RAW via LDS, row = own q)
    unsigned int rhp = *(const unsigned int*)&RHb[qloc][kt * 2];
    float rh0 = bfu2f(rhp & 0xffffu), rh1 = bfhi2f(rhp);
    __syncthreads();

    // S^T = K.Q^T + (rh+rw) ; rows k = quad*4+reg (+nt*16), col q = qloc
    floatx4 st[4];
#pragma unroll
    for (int nt = 0; nt < 4; ++nt) {
      int r = nt * 16 + c16;
      bf16x8 bk0 = *(bf16x8*)&Ks[r * 64 + (quad ^ sw) * 8];
      bf16x8 bk1 = *(bf16x8*)&Ks[r * 64 + ((4 + quad) ^ sw) * 8];
      floatx4 ci;
      float rh = (nt < 2) ? rh0 : rh1;
#pragma unroll
      for (int reg = 0; reg < 4; ++reg) ci[reg] = rh + rwv[nt & 1][reg];
      st[nt] = MFMA16(bk1, aq1, MFMA16(bk0, aq0, ci));
    }

#pragma unroll
    for (int nt = 0; nt < 4; ++nt) {
      float4 pm = *(const float4*)&polf[kt * 64 + nt * 16 + quad * 4];
      float e0, e1, e2, e3;
      if (kt != ktq) {
        e0 = exp2f(st[nt][0]) * pm.x; e1 = exp2f(st[nt][1]) * pm.y;
        e2 = exp2f(st[nt][2]) * pm.z; e3 = exp2f(st[nt][3]) * pm.w;
      } else {
        int kb = nt * 16 + quad * 4;
        e0 = exp2f(st[nt][0]) * ((kb + 0 == kdiag) ? 1.f : pm.x);
        e1 = exp2f(st[nt][1]) * ((kb + 1 == kdiag) ? 1.f : pm.y);
        e2 = exp2f(st[nt][2]) * ((kb + 2 == kdiag) ? 1.f : pm.z);
        e3 = exp2f(st[nt][3]) * ((kb + 3 == kdiag) ? 1.f : pm.w);
      }
      l_lane += (e0 + e1) + (e2 + e3);
      bf16x4 pe = {(bf16)e0, (bf16)e1, (bf16)e2, (bf16)e3};
      *(bf16x4*)&Ptw[ptoff[nt]] = pe;
    }

    // PV: O += P.V (wave-private strip; same-wave RAW)
#pragma unroll
    for (int kw2 = 0; kw2 < 2; ++kw2) {
      bf16x8 ap = *(bf16x8*)&Ptw[c16 * 64 + ((kw2 * 4 + quad) ^ sw) * 8];
#pragma unroll
      for (int dt = 0; dt < 4; ++dt) {
        int r = dt * 16 + c16;
        bf16x8 bv = *(bf16x8*)&Vt[r * 64 + ((kw2 * 4 + quad) ^ sw) * 8];
        o_acc[dt] = MFMA16(ap, bv, o_acc[dt]);
      }
    }
  }

  // row-sum lives per-lane (col q): reduce across quads, then distribute
  float l = l_lane;
  l += __shfl_xor(l, 16, 64);
  l += __shfl_xor(l, 32, 64);
  float invl = 1.f / (l + EPS_);
  float inv[4];
#pragma unroll
  for (int reg = 0; reg < 4; ++reg) inv[reg] = __shfl(invl, quad * 4 + reg, 64);

#pragma unroll
  for (int dt = 0; dt < 4; ++dt) {
    int d = dt * 16 + c16;
    float vs = Vsum[bh * 64 + d];
#pragma unroll
    for (int reg = 0; reg < 4; ++reg) {
      int nq = qt * 128 + wid * 16 + quad * 4 + reg;
      float o = (o_acc[dt][reg] + EPSN_ * vs) * inv[reg];
      AO[((size_t)b * N_ + nq) * C_ + head * HD_ + d] = (bf16)o;
    }
  }
}

// ---------------------------------------------------------------------------
// Proj GEMM (m97 recipe, flip orientation -> float4 stores)
// ---------------------------------------------------------------------------
__global__ __launch_bounds__(256) void gemm_proj(
    const bf16* __restrict__ A, const bf16* __restrict__ W,
    const float* __restrict__ bias, float* __restrict__ Out) {
  __shared__ __align__(16) bf16 As[128 * 64];
  __shared__ __align__(16) bf16 Bs[128 * 64];
  const int tid = threadIdx.x;
  const int lane = tid & 63, quad = lane >> 4, c16 = lane & 15;
  const int wid = tid >> 6;
  const int wm = (wid >> 1) * 64, wn = (wid & 1) * 64;
  const int m0 = blockIdx.x * 128, n0 = blockIdx.y * 128;
  floatx4 acc[4][4];
#pragma unroll
  for (int i = 0; i < 4; ++i)
#pragma unroll
    for (int j = 0; j < 4; ++j) acc[i][j] = {0.f, 0.f, 0.f, 0.f};

  for (int k0 = 0; k0 < 768; k0 += 64) {
    __syncthreads();
#pragma unroll
    for (int t = 0; t < 4; ++t) {
      int task = t * 256 + tid;
      int r = task >> 3, lg = (task & 7) ^ (r & 7);
      int wbase = (t * 256 + (tid & 192)) * 8;
      gld16(A + (size_t)(m0 + r) * 768 + k0 + lg * 8, &As[wbase]);
      gld16(W + (size_t)(n0 + r) * 768 + k0 + lg * 8, &Bs[wbase]);
    }
    __syncthreads();
#pragma unroll
    for (int kw = 0; kw < 2; ++kw) {
      bf16x8 af[4], bfr[4];
#pragma unroll
      for (int i = 0; i < 4; ++i) {
        int r = wm + i * 16 + c16, pg = (kw * 4 + quad) ^ (c16 & 7);
        af[i] = *(bf16x8*)&As[r * 64 + pg * 8];
      }
#pragma unroll
      for (int j = 0; j < 4; ++j) {
        int r = wn + j * 16 + c16, pg = (kw * 4 + quad) ^ (c16 & 7);
        bfr[j] = *(bf16x8*)&Bs[r * 64 + pg * 8];
      }
#pragma unroll
      for (int a = 0; a < 4; ++a)
#pragma unroll
        for (int b = 0; b < 4; ++b) acc[a][b] = MFMA16(bfr[a], af[b], acc[a][b]);
    }
  }
#pragma unroll
  for (int a = 0; a < 4; ++a) {
    int jb = n0 + wn + a * 16 + quad * 4;
    float4 b4 = *(const float4*)&bias[jb];
#pragma unroll
    for (int b = 0; b < 4; ++b) {
      int m = m0 + wm + b * 16 + c16;
      float4 o = make_float4(acc[a][b][0] + b4.x, acc[a][b][1] + b4.y,
                             acc[a][b][2] + b4.z, acc[a][b][3] + b4.w);
      *(float4*)&Out[(size_t)m * 768 + jb] = o;
    }
  }
}

extern "C" void kernel_launch(void* const* d_in, const int* in_sizes, int n_in,
                              void* d_out, int out_size, void* d_ws, size_t ws_size,
                              hipStream_t stream) {
  const float* x      = (const float*)d_in[0];
  const float* policy = (const float*)d_in[1];
  const float* qkv_w  = (const float*)d_in[2];
  const float* qkv_b  = (const float*)d_in[3];
  const float* proj_w = (const float*)d_in[4];
  const float* proj_b = (const float*)d_in[5];
  const float* relh   = (const float*)d_in[6];
  const float* relw   = (const float*)d_in[7];

  char* ws = (char*)d_ws;
  bf16* Xbf   = (bf16*)(ws);                    // 12,582,912 B
  bf16* Wqkv  = (bf16*)(ws + 12582912);         //  3,538,944 B
  bf16* Wproj = (bf16*)(ws + 16121856);         //  1,179,648 B
  bf16* Rhb   = (bf16*)(ws + 17301504);         //      8,192 B
  bf16* Rwb   = (bf16*)(ws + 17309696);         //      8,192 B
  bf16* Qb    = (bf16*)(ws + 17317888);         // 12,582,912 B
  bf16* Kb    = (bf16*)(ws + 29900800);
  bf16* Vb    = (bf16*)(ws + 42483712);         // [bh][d][n] layout
  bf16* AOb   = (bf16*)(ws + 55066624);
  float* Vsum = (float*)(ws + 67649536);        //     24,576 B

  hipMemsetAsync(Vsum, 0, BH_ * HD_ * sizeof(float), stream);
  prep_kernel<<<8480, 256, 0, stream>>>(x, qkv_w, proj_w, relh, relw,
                                        Xbf, Wqkv, Wproj, Rhb, Rwb);
  gemm_qkv<<<dim3(64, 18), 256, 0, stream>>>(Xbf, Wqkv, qkv_b, Qb, Kb, Vb, Vsum);
  attn_mfma<<<dim3(BH_, 8), 512, 0, stream>>>(Qb, Kb, Vb, policy, Rhb, Rwb,
                                              Vsum, AOb);
  gemm_proj<<<dim3(64, 6), 256, 0, stream>>>(AOb, Wproj, proj_b, (float*)d_out);
}

// Round 9
// 226.619 us; speedup vs baseline: 1.1996x; 1.1996x over previous
//
#include <hip/hip_runtime.h>
#include <hip/hip_bf16.h>

// Problem constants (reference: DIM=768, NUM_HEADS=12, HEAD_DIM=64, GRID=32, B=8)
#define B_   8
#define N_   1024
#define C_   768
#define NH_  12
#define HD_  64
#define BH_  96
#define EPS_ 1e-6f
#define EPSN_ (1e-6f / 1024.0f)
#define SQ_  0.1803368801111244f   // 0.125 * log2(e) — Q pre-scale

typedef __bf16 bf16;
typedef __attribute__((ext_vector_type(8))) __bf16  bf16x8;
typedef __attribute__((ext_vector_type(4))) __bf16  bf16x4;
typedef __attribute__((ext_vector_type(4))) float   floatx4;

#define MFMA16(a, b, c) __builtin_amdgcn_mfma_f32_16x16x32_bf16((a), (b), (c), 0, 0, 0)

__device__ __forceinline__ void gld16(const void* g, void* l) {
  typedef unsigned int u32;
  __builtin_amdgcn_global_load_lds(
      (const __attribute__((address_space(1))) u32*)g,
      (__attribute__((address_space(3))) u32*)l, 16, 0, 0);
}
__device__ __forceinline__ float bfu2f(unsigned int u) {   // low 16 bits = bf16
  union { unsigned int i; float f; } v; v.i = u << 16; return v.f;
}
__device__ __forceinline__ float bfhi2f(unsigned int u) {  // high 16 bits = bf16
  union { unsigned int i; float f; } v; v.i = u & 0xffff0000u; return v.f;
}
__device__ __forceinline__ unsigned short f2bfu(float f) {
  union { float f; unsigned int i; } v; v.f = f;
  return (unsigned short)((v.i + 0x7FFFu + ((v.i >> 16) & 1u)) >> 16);
}

// ---------------------------------------------------------------------------
// Fused prep: x/qkv_w/proj_w fp32->bf16, rel tables fp32->bf16 scaled by 8.
// ---------------------------------------------------------------------------
__global__ __launch_bounds__(256) void prep_kernel(
    const float* __restrict__ x, const float* __restrict__ qkv_w,
    const float* __restrict__ proj_w, const float* __restrict__ relh,
    const float* __restrict__ relw,
    bf16* __restrict__ Xb, bf16* __restrict__ Wq, bf16* __restrict__ Wp,
    bf16* __restrict__ Rhb, bf16* __restrict__ Rwb) {
  int bid = blockIdx.x;
  if (bid < 8448) {                 // bulk converts
    const float* in; bf16* out; int i;
    if (bid < 6144)      { in = x;      out = Xb; i = bid * 256 + threadIdx.x; }
    else if (bid < 7872) { in = qkv_w;  out = Wq; i = (bid - 6144) * 256 + threadIdx.x; }
    else                 { in = proj_w; out = Wp; i = (bid - 7872) * 256 + threadIdx.x; }
    float4 v = ((const float4*)in)[i];
    bf16x4 o = {(bf16)v.x, (bf16)v.y, (bf16)v.z, (bf16)v.w};
    ((bf16x4*)out)[i] = o;
  } else {                          // rel tables: 63x64 -> 64x64, x8 scale
    const float* in = (bid < 8464) ? relh : relw;
    bf16* out = (bid < 8464) ? Rhb : Rwb;
    int i = ((bid < 8464) ? (bid - 8448) : (bid - 8464)) * 256 + threadIdx.x;
    int r = i >> 6;
    out[i] = (r < 63) ? (bf16)(in[i] * 8.0f) : (bf16)0.0f;
  }
}

// ---------------------------------------------------------------------------
// QKV GEMM, double-buffered LDS: stage iter i+1 while computing iter i, one
// barrier per iter -> the compiler's vmcnt(0)-before-barrier lands AFTER the
// compute phase, overlapping loads with MFMA (the R8 counters showed the
// 2-barrier loop drain-bound: MfmaUtil 11%, everything idle).
// Q/K blocks flipped (packed d stores); V blocks normal (packed n stores
// into [bh][d][n]).
// ---------------------------------------------------------------------------
__global__ __launch_bounds__(256) void gemm_qkv(
    const bf16* __restrict__ X, const bf16* __restrict__ W,
    const float* __restrict__ bias,
    bf16* __restrict__ Qb, bf16* __restrict__ Kb, bf16* __restrict__ Vb) {
  __shared__ __align__(16) bf16 As[2][8192];
  __shared__ __align__(16) bf16 Bs[2][8192];
  const int tid = threadIdx.x;
  const int lane = tid & 63, quad = lane >> 4, c16 = lane & 15;
  const int wid = tid >> 6;
  const int wm = (wid >> 1) * 64, wn = (wid & 1) * 64;
  const int m0 = blockIdx.x * 128, n0 = blockIdx.y * 128;
  const bool flip = (blockIdx.y < 12);    // Q and K column blocks
  floatx4 acc[4][4];
#pragma unroll
  for (int i = 0; i < 4; ++i)
#pragma unroll
    for (int j = 0; j < 4; ++j) acc[i][j] = {0.f, 0.f, 0.f, 0.f};

  auto stage = [&](int k0, int buf) {
#pragma unroll
    for (int t = 0; t < 4; ++t) {
      int task = t * 256 + tid;
      int r = task >> 3, lg = (task & 7) ^ (r & 7);
      int wbase = (t * 256 + (tid & 192)) * 8;
      gld16(X + (size_t)(m0 + r) * 768 + k0 + lg * 8, &As[buf][wbase]);
      gld16(W + (size_t)(n0 + r) * 768 + k0 + lg * 8, &Bs[buf][wbase]);
    }
  };

  stage(0, 0);
  for (int it = 0; it < 12; ++it) {
    const int cur = it & 1;
    __syncthreads();                       // drains stage(it); orders WAR for it+1
    if (it < 11) stage((it + 1) * 64, cur ^ 1);
#pragma unroll
    for (int kw = 0; kw < 2; ++kw) {
      bf16x8 af[4], bfr[4];
#pragma unroll
      for (int i = 0; i < 4; ++i) {
        int r = wm + i * 16 + c16, pg = (kw * 4 + quad) ^ (c16 & 7);
        af[i] = *(bf16x8*)&As[cur][r * 64 + pg * 8];
      }
#pragma unroll
      for (int j = 0; j < 4; ++j) {
        int r = wn + j * 16 + c16, pg = (kw * 4 + quad) ^ (c16 & 7);
        bfr[j] = *(bf16x8*)&Bs[cur][r * 64 + pg * 8];
      }
      if (flip) {
#pragma unroll
        for (int a = 0; a < 4; ++a)
#pragma unroll
          for (int b = 0; b < 4; ++b) acc[a][b] = MFMA16(bfr[a], af[b], acc[a][b]);
      } else {
#pragma unroll
        for (int i = 0; i < 4; ++i)
#pragma unroll
          for (int j = 0; j < 4; ++j) acc[i][j] = MFMA16(af[i], bfr[j], acc[i][j]);
      }
    }
  }
  if (flip) {
    const bool isQ = (blockIdx.y < 6);
    bf16* base = isQ ? Qb : Kb;
    const int off = isQ ? 0 : 768;
#pragma unroll
    for (int a = 0; a < 4; ++a) {
      int jb = n0 + wn + a * 16 + quad * 4;
      float4 b4 = *(const float4*)&bias[jb];
      int head = (jb - off) >> 6;
      int d = jb & 63;
#pragma unroll
      for (int b = 0; b < 4; ++b) {
        int tok = m0 + wm + b * 16 + c16;
        int bb = tok >> 10, n = tok & 1023;
        float v0 = acc[a][b][0] + b4.x, v1 = acc[a][b][1] + b4.y;
        float v2 = acc[a][b][2] + b4.z, v3 = acc[a][b][3] + b4.w;
        if (isQ) { v0 *= SQ_; v1 *= SQ_; v2 *= SQ_; v3 *= SQ_; }
        bf16x4 o = {(bf16)v0, (bf16)v1, (bf16)v2, (bf16)v3};
        *(bf16x4*)&base[(((size_t)bb * NH_ + head) * N_ + n) * HD_ + d] = o;
      }
    }
  } else {
#pragma unroll
    for (int jt = 0; jt < 4; ++jt) {
      int j = n0 + wn + jt * 16 + c16;
      float bj = bias[j];
      int rem = j - 1536, head = rem >> 6, d = rem & 63;
#pragma unroll
      for (int it = 0; it < 4; ++it) {
        int mbase = m0 + wm + it * 16 + quad * 4;
        int bb = mbase >> 10, n = mbase & 1023;
        bf16x4 o = {(bf16)(acc[it][jt][0] + bj), (bf16)(acc[it][jt][1] + bj),
                    (bf16)(acc[it][jt][2] + bj), (bf16)(acc[it][jt][3] + bj)};
        *(bf16x4*)&Vb[(((size_t)bb * NH_ + head) * HD_ + d) * N_ + n] = o;
      }
    }
  }
}

// ---------------------------------------------------------------------------
// Vsum[bh][d] = sum_n V[bh][d][n]  (fp32)
// ---------------------------------------------------------------------------
__global__ __launch_bounds__(256) void vsum_kernel(const bf16* __restrict__ Vb,
                                                   float* __restrict__ Vsum) {
  const int bh = blockIdx.x;
  const int d = threadIdx.x >> 2, part = threadIdx.x & 3;
  const bf16* Vg = Vb + (size_t)bh * (N_ * HD_) + d * N_ + part * 256;
  float s = 0.f;
  for (int i = 0; i < 32; ++i) {
    bf16x8 v = *(const bf16x8*)(Vg + i * 8);
#pragma unroll
    for (int e = 0; e < 8; ++e) s += (float)v[e];
  }
  __shared__ float red[64][4];
  red[d][part] = s;
  __syncthreads();
  if (part == 0) Vsum[bh * 64 + d] = red[d][0] + red[d][1] + red[d][2] + red[d][3];
}

// ---------------------------------------------------------------------------
// Flash attention (R7 form — measured 74.4 µs, 4 blocks/CU). rel-pos folded
// into QK^T accumulator init; P-strip write offsets hoisted (kt-invariant).
// ---------------------------------------------------------------------------
__global__ __launch_bounds__(256, 4) void attn_mfma(
    const bf16* __restrict__ Qb, const bf16* __restrict__ Kb,
    const bf16* __restrict__ Vb, const float* __restrict__ policy,
    const bf16* __restrict__ Rh, const bf16* __restrict__ Rw,
    const float* __restrict__ Vsum, bf16* __restrict__ AO) {
  const int bh = blockIdx.x, qt = blockIdx.y;
  const int b = bh / NH_, head = bh % NH_;
  __shared__ __align__(16) bf16 Qs[4096];       // aliased by Pt after frag load
  __shared__ __align__(16) bf16 Ks[4096];       // Rh, Rw, then K tiles
  __shared__ __align__(16) bf16 Vt[4096];       // V tile [d][k]
  __shared__ unsigned short RHb[64][34];        // bf16 bits
  __shared__ unsigned short RWb[64][34];
  __shared__ float polf[1024];
  const int tid = threadIdx.x;
  const int wid = tid >> 6, lane = tid & 63, quad = lane >> 4, c16 = lane & 15;
  const int sw = c16 & 7;
  bf16* Ptw = Qs + wid * 1024;                  // wave-private [16][64] strip
  const floatx4 zero4 = {0.f, 0.f, 0.f, 0.f};

  const bf16* Qg = Qb + ((size_t)bh * N_ + qt * 64) * HD_;
  const bf16* Kg = Kb + (size_t)bh * (N_ * HD_);
  const bf16* Vg = Vb + (size_t)bh * (N_ * HD_);

  // stage Q, Rh (into Ks), policy row
#pragma unroll
  for (int t = 0; t < 2; ++t) {
    int task = t * 256 + tid;
    int r = task >> 3, lg = (task & 7) ^ (r & 7);
    int wbase = (t * 256 + (tid & 192)) * 8;
    gld16(Qg + r * 64 + lg * 8, &Qs[wbase]);
    gld16(Rh + r * 64 + lg * 8, &Ks[wbase]);
  }
  gld16(policy + (size_t)b * N_ + tid * 4, &polf[(tid & 192) * 4]);
  __syncthreads();

  bf16x8 aq0 = *(bf16x8*)&Qs[(wid * 16 + c16) * 64 + (quad ^ sw) * 8];
  bf16x8 aq1 = *(bf16x8*)&Qs[(wid * 16 + c16) * 64 + ((4 + quad) ^ sw) * 8];

  // QRh -> RHb[r][krow] (bf16 bits; rows wave-private)
  {
    floatx4 racc[4];
#pragma unroll
    for (int nt = 0; nt < 4; ++nt) {
      int r = nt * 16 + c16;
      bf16x8 b0 = *(bf16x8*)&Ks[r * 64 + (quad ^ sw) * 8];
      bf16x8 b1 = *(bf16x8*)&Ks[r * 64 + ((4 + quad) ^ sw) * 8];
      racc[nt] = MFMA16(aq1, b1, MFMA16(aq0, b0, zero4));
    }
#pragma unroll
    for (int nt = 0; nt < 4; ++nt)
#pragma unroll
      for (int reg = 0; reg < 4; ++reg) {
        int rloc = wid * 16 + quad * 4 + reg;
        int hh = 2 * qt + (rloc >> 5);
        int krow = hh + 31 - (nt * 16 + c16);
        if ((unsigned)krow < 32u) RHb[rloc][krow] = f2bfu(racc[nt][reg]);
      }
  }
  __syncthreads();
#pragma unroll
  for (int t = 0; t < 2; ++t) {
    int task = t * 256 + tid;
    int r = task >> 3, lg = (task & 7) ^ (r & 7);
    gld16(Rw + r * 64 + lg * 8, &Ks[(t * 256 + (tid & 192)) * 8]);
  }
  __syncthreads();
  // QRw -> RWb[r][kcol]
  {
    floatx4 racc[4];
#pragma unroll
    for (int nt = 0; nt < 4; ++nt) {
      int r = nt * 16 + c16;
      bf16x8 b0 = *(bf16x8*)&Ks[r * 64 + (quad ^ sw) * 8];
      bf16x8 b1 = *(bf16x8*)&Ks[r * 64 + ((4 + quad) ^ sw) * 8];
      racc[nt] = MFMA16(aq1, b1, MFMA16(aq0, b0, zero4));
    }
#pragma unroll
    for (int nt = 0; nt < 4; ++nt)
#pragma unroll
      for (int reg = 0; reg < 4; ++reg) {
        int rloc = wid * 16 + quad * 4 + reg;
        int kcol = (rloc & 31) + 31 - (nt * 16 + c16);
        if ((unsigned)kcol < 32u) RWb[rloc][kcol] = f2bfu(racc[nt][reg]);
      }
  }

  // hoist rw (kt-invariant); same-wave RAW through LDS
  float rwv0[4], rwv1[4];
#pragma unroll
  for (int reg = 0; reg < 4; ++reg) {
    int rloc = wid * 16 + quad * 4 + reg;
    rwv0[reg] = bfu2f(RWb[rloc][c16]);
    rwv1[reg] = bfu2f(RWb[rloc][16 + c16]);
  }
  // hoist Pt write offsets (kt-invariant)
  int ptoff[4][4];
#pragma unroll
  for (int reg = 0; reg < 4; ++reg) {
    int prow = quad * 4 + reg;
#pragma unroll
    for (int nt = 0; nt < 4; ++nt)
      ptoff[reg][nt] = prow * 64 + (c16 & 7) +
                       (((nt * 2 + (c16 >> 3)) ^ (prow & 7)) << 3);
  }

  float l_part[4] = {0.f, 0.f, 0.f, 0.f};
  floatx4 o_acc[4];
#pragma unroll
  for (int i = 0; i < 4; ++i) o_acc[i] = zero4;
  int nqr[4];
#pragma unroll
  for (int reg = 0; reg < 4; ++reg) nqr[reg] = qt * 64 + wid * 16 + quad * 4 + reg;

  for (int kt = 0; kt < 16; ++kt) {
    __syncthreads();
#pragma unroll
    for (int t = 0; t < 2; ++t) {
      int task = t * 256 + tid;
      int r = task >> 3, lg = (task & 7) ^ (r & 7);
      int wbase = (t * 256 + (tid & 192)) * 8;
      gld16(Kg + (size_t)(kt * 64 + r) * 64 + lg * 8, &Ks[wbase]);
      gld16(Vg + (size_t)r * N_ + kt * 64 + lg * 8, &Vt[wbase]);
    }

    // build C-init = rh + rw while loads are in flight
    floatx4 init[4];
#pragma unroll
    for (int reg = 0; reg < 4; ++reg) {
      int rloc = wid * 16 + quad * 4 + reg;
      unsigned int rhp = *(const unsigned int*)&RHb[rloc][kt * 2];
      float rh0 = bfu2f(rhp & 0xffffu), rh1 = bfhi2f(rhp);
      init[0][reg] = rh0 + rwv0[reg];
      init[1][reg] = rh0 + rwv1[reg];
      init[2][reg] = rh1 + rwv0[reg];
      init[3][reg] = rh1 + rwv1[reg];
    }
    float pm[4];
#pragma unroll
    for (int nt = 0; nt < 4; ++nt) pm[nt] = polf[kt * 64 + nt * 16 + c16];
    __syncthreads();

    // S = Q.K^T + (rh+rw) via C-init; score already in exp2 units
    floatx4 s[4];
#pragma unroll
    for (int nt = 0; nt < 4; ++nt) {
      int r = nt * 16 + c16;
      bf16x8 bk0 = *(bf16x8*)&Ks[r * 64 + (quad ^ sw) * 8];
      bf16x8 bk1 = *(bf16x8*)&Ks[r * 64 + ((4 + quad) ^ sw) * 8];
      s[nt] = MFMA16(aq1, bk1, MFMA16(aq0, bk0, init[nt]));
    }

#pragma unroll
    for (int reg = 0; reg < 4; ++reg) {
      if (kt != qt) {
#pragma unroll
        for (int nt = 0; nt < 4; ++nt) {
          float e = exp2f(s[nt][reg]) * pm[nt];
          l_part[reg] += e;
          Ptw[ptoff[reg][nt]] = (bf16)e;
        }
      } else {
        const int nq = nqr[reg];
#pragma unroll
        for (int nt = 0; nt < 4; ++nt) {
          int kg = kt * 64 + nt * 16 + c16;
          float mask = (kg == nq) ? 1.f : pm[nt];
          float e = exp2f(s[nt][reg]) * mask;
          l_part[reg] += e;
          Ptw[ptoff[reg][nt]] = (bf16)e;
        }
      }
    }

    // PV: O += P.V (wave-private strip)
#pragma unroll
    for (int kw2 = 0; kw2 < 2; ++kw2) {
      bf16x8 ap = *(bf16x8*)&Ptw[c16 * 64 + ((kw2 * 4 + quad) ^ sw) * 8];
#pragma unroll
      for (int dt = 0; dt < 4; ++dt) {
        int r = dt * 16 + c16;
        bf16x8 bv = *(bf16x8*)&Vt[r * 64 + ((kw2 * 4 + quad) ^ sw) * 8];
        o_acc[dt] = MFMA16(ap, bv, o_acc[dt]);
      }
    }
  }

  float inv[4];
#pragma unroll
  for (int reg = 0; reg < 4; ++reg) {
    float l = l_part[reg];
#pragma unroll
    for (int d = 1; d < 16; d <<= 1) l += __shfl_xor(l, d, 64);
    inv[reg] = 1.f / (l + EPS_);
  }
#pragma unroll
  for (int dt = 0; dt < 4; ++dt) {
    int d = dt * 16 + c16;
    float vs = Vsum[bh * 64 + d];
#pragma unroll
    for (int reg = 0; reg < 4; ++reg) {
      float o = (o_acc[dt][reg] + EPSN_ * vs) * inv[reg];
      AO[((size_t)b * N_ + nqr[reg]) * C_ + head * HD_ + d] = (bf16)o;
    }
  }
}

// ---------------------------------------------------------------------------
// Proj GEMM, double-buffered LDS, flip orientation (float4 stores).
// ---------------------------------------------------------------------------
__global__ __launch_bounds__(256) void gemm_proj(
    const bf16* __restrict__ A, const bf16* __restrict__ W,
    const float* __restrict__ bias, float* __restrict__ Out) {
  __shared__ __align__(16) bf16 As[2][8192];
  __shared__ __align__(16) bf16 Bs[2][8192];
  const int tid = threadIdx.x;
  const int lane = tid & 63, quad = lane >> 4, c16 = lane & 15;
  const int wid = tid >> 6;
  const int wm = (wid >> 1) * 64, wn = (wid & 1) * 64;
  const int m0 = blockIdx.x * 128, n0 = blockIdx.y * 128;
  floatx4 acc[4][4];
#pragma unroll
  for (int i = 0; i < 4; ++i)
#pragma unroll
    for (int j = 0; j < 4; ++j) acc[i][j] = {0.f, 0.f, 0.f, 0.f};

  auto stage = [&](int k0, int buf) {
#pragma unroll
    for (int t = 0; t < 4; ++t) {
      int task = t * 256 + tid;
      int r = task >> 3, lg = (task & 7) ^ (r & 7);
      int wbase = (t * 256 + (tid & 192)) * 8;
      gld16(A + (size_t)(m0 + r) * 768 + k0 + lg * 8, &As[buf][wbase]);
      gld16(W + (size_t)(n0 + r) * 768 + k0 + lg * 8, &Bs[buf][wbase]);
    }
  };

  stage(0, 0);
  for (int it = 0; it < 12; ++it) {
    const int cur = it & 1;
    __syncthreads();
    if (it < 11) stage((it + 1) * 64, cur ^ 1);
#pragma unroll
    for (int kw = 0; kw < 2; ++kw) {
      bf16x8 af[4], bfr[4];
#pragma unroll
      for (int i = 0; i < 4; ++i) {
        int r = wm + i * 16 + c16, pg = (kw * 4 + quad) ^ (c16 & 7);
        af[i] = *(bf16x8*)&As[cur][r * 64 + pg * 8];
      }
#pragma unroll
      for (int j = 0; j < 4; ++j) {
        int r = wn + j * 16 + c16, pg = (kw * 4 + quad) ^ (c16 & 7);
        bfr[j] = *(bf16x8*)&Bs[cur][r * 64 + pg * 8];
      }
#pragma unroll
      for (int a = 0; a < 4; ++a)
#pragma unroll
        for (int b = 0; b < 4; ++b) acc[a][b] = MFMA16(bfr[a], af[b], acc[a][b]);
    }
  }
#pragma unroll
  for (int a = 0; a < 4; ++a) {
    int jb = n0 + wn + a * 16 + quad * 4;
    float4 b4 = *(const float4*)&bias[jb];
#pragma unroll
    for (int b = 0; b < 4; ++b) {
      int m = m0 + wm + b * 16 + c16;
      float4 o = make_float4(acc[a][b][0] + b4.x, acc[a][b][1] + b4.y,
                             acc[a][b][2] + b4.z, acc[a][b][3] + b4.w);
      *(float4*)&Out[(size_t)m * 768 + jb] = o;
    }
  }
}

extern "C" void kernel_launch(void* const* d_in, const int* in_sizes, int n_in,
                              void* d_out, int out_size, void* d_ws, size_t ws_size,
                              hipStream_t stream) {
  const float* x      = (const float*)d_in[0];
  const float* policy = (const float*)d_in[1];
  const float* qkv_w  = (const float*)d_in[2];
  const float* qkv_b  = (const float*)d_in[3];
  const float* proj_w = (const float*)d_in[4];
  const float* proj_b = (const float*)d_in[5];
  const float* relh   = (const float*)d_in[6];
  const float* relw   = (const float*)d_in[7];

  char* ws = (char*)d_ws;
  bf16* Xbf   = (bf16*)(ws);                    // 12,582,912 B
  bf16* Wqkv  = (bf16*)(ws + 12582912);         //  3,538,944 B
  bf16* Wproj = (bf16*)(ws + 16121856);         //  1,179,648 B
  bf16* Rhb   = (bf16*)(ws + 17301504);         //      8,192 B
  bf16* Rwb   = (bf16*)(ws + 17309696);         //      8,192 B
  bf16* Qb    = (bf16*)(ws + 17317888);         // 12,582,912 B
  bf16* Kb    = (bf16*)(ws + 29900800);
  bf16* Vb    = (bf16*)(ws + 42483712);         // [bh][d][n] layout
  bf16* AOb   = (bf16*)(ws + 55066624);
  float* Vsum = (float*)(ws + 67649536);        //     24,576 B

  prep_kernel<<<8480, 256, 0, stream>>>(x, qkv_w, proj_w, relh, relw,
                                        Xbf, Wqkv, Wproj, Rhb, Rwb);
  gemm_qkv<<<dim3(64, 18), 256, 0, stream>>>(Xbf, Wqkv, qkv_b, Qb, Kb, Vb);
  vsum_kernel<<<BH_, 256, 0, stream>>>(Vb, Vsum);
  attn_mfma<<<dim3(BH_, 16), 256, 0, stream>>>(Qb, Kb, Vb, policy, Rhb, Rwb,
                                               Vsum, AOb);
  gemm_proj<<<dim3(64, 6), 256, 0, stream>>>(AOb, Wproj, proj_b, (float*)d_out);
}